// Round 1
// baseline (463.869 us; speedup 1.0000x reference)
//
#include <hip/hip_runtime.h>
#include <math.h>

#define HW 65536  // 256*256

// ---------------- K1: in_conv 1x1, 64 -> 16 ----------------
__global__ __launch_bounds__(256) void k_inconv(const float* __restrict__ cen,
                                                const float* __restrict__ w,
                                                const float* __restrict__ bias,
                                                float* __restrict__ x) {
    __shared__ float sw[1024];
    __shared__ float sb[16];
    int tid = threadIdx.x;
    for (int i = tid; i < 1024; i += 256) sw[i] = w[i];
    if (tid < 16) sb[tid] = bias[tid];
    __syncthreads();

    long t  = (long)blockIdx.x * 256 + tid;   // quad index
    long p0 = t * 4;                          // first pixel (b*HW + hw)
    int  b  = (int)(p0 >> 16);
    int  hw = (int)(p0 & 65535);

    const float4* src = (const float4*)(cen + ((long)b * 64) * HW + hw);
    float4 acc[16];
#pragma unroll
    for (int o = 0; o < 16; o++) { float bv = sb[o]; acc[o] = make_float4(bv, bv, bv, bv); }

    for (int i = 0; i < 64; i++) {
        float4 v = src[(long)i * (HW / 4)];
#pragma unroll
        for (int o = 0; o < 16; o++) {
            float wv = sw[o * 64 + i];
            acc[o].x = fmaf(v.x, wv, acc[o].x);
            acc[o].y = fmaf(v.y, wv, acc[o].y);
            acc[o].z = fmaf(v.z, wv, acc[o].z);
            acc[o].w = fmaf(v.w, wv, acc[o].w);
        }
    }
    float4* dst = (float4*)(x + ((long)b * 16) * HW + hw);
#pragma unroll
    for (int o = 0; o < 16; o++) dst[(long)o * (HW / 4)] = acc[o];
}

// ---------------- K2: per-(b,c) fused branch machinery ----------------
#define CE(a, b) { float _lo = fminf(a, b); float _hi = fmaxf(a, b); a = _lo; b = _hi; }

__device__ __forceinline__ void sort8(float* v) {
    CE(v[0], v[1]); CE(v[2], v[3]); CE(v[4], v[5]); CE(v[6], v[7]);
    CE(v[0], v[2]); CE(v[1], v[3]); CE(v[4], v[6]); CE(v[5], v[7]);
    CE(v[1], v[2]); CE(v[5], v[6]); CE(v[0], v[4]); CE(v[3], v[7]);
    CE(v[1], v[5]); CE(v[2], v[6]);
    CE(v[1], v[4]); CE(v[3], v[6]);
    CE(v[2], v[4]); CE(v[3], v[5]);
    CE(v[3], v[4]);
}
__device__ __forceinline__ void sort4(float* v) {
    CE(v[0], v[1]); CE(v[2], v[3]); CE(v[0], v[2]); CE(v[1], v[3]); CE(v[1], v[2]);
}

__global__ __launch_bounds__(256) void k_main(
    const float* __restrict__ x,
    const float* __restrict__ dw_w1, const float* __restrict__ dw_b1,
    const float* __restrict__ dw_w3, const float* __restrict__ dw_b3,
    const float* __restrict__ dw_w5, const float* __restrict__ dw_b5,
    const float* __restrict__ dw_w7, const float* __restrict__ dw_b7,
    const float* __restrict__ l1w, const float* __restrict__ l1b,
    const float* __restrict__ l2w, const float* __restrict__ l2b,
    const float* __restrict__ bw,  const float* __restrict__ bns,
    const float* __restrict__ bnb, float* __restrict__ y16) {

    const int plane = blockIdx.y;          // b*16 + c
    const int c     = plane & 15;
    const int ty0   = (blockIdx.x >> 3) * 32;
    const int tx0   = (blockIdx.x & 7) * 32;
    const int tid   = threadIdx.x;

    __shared__ float lx[53 * 53];          // x tile + halo 10, stride 53
    __shared__ float lxs[4][46 * 47];      // 4 dw-conv outputs, tile + halo 7, stride 47

    const float* xp = x + (long)plane * HW;

    // ---- stage x tile (52x52, origin (ty0-10, tx0-10)), zero outside image ----
    for (int i = tid; i < 52 * 52; i += 256) {
        int r  = i / 52;
        int cc = i - r * 52;
        int gy = ty0 - 10 + r, gx = tx0 - 10 + cc;
        float v = 0.f;
        if (gy >= 0 && gy < 256 && gx >= 0 && gx < 256) v = xp[gy * 256 + gx];
        lx[r * 53 + cc] = v;
    }
    __syncthreads();

    // ---- compute 4 depthwise convs into lxs over 46x46 (tile + halo 7) ----
    const float* W7 = dw_w7 + c * 49;
    const float* W5 = dw_w5 + c * 25;
    const float* W3 = dw_w3 + c * 9;
    const float  W1 = dw_w1[c];
    const float  B1 = dw_b1[c], B3 = dw_b3[c], B5 = dw_b5[c], B7 = dw_b7[c];

    for (int u = tid; u < 552; u += 256) {      // 46 rows x 12 groups of 4 cols
        int row = u % 46;
        int grp = u / 46;
        int pc0 = grp * 4;
        float c7[4] = {0, 0, 0, 0}, c5[4] = {0, 0, 0, 0}, c3[4] = {0, 0, 0, 0};
        float c1[4] = {0, 0, 0, 0};
#pragma unroll
        for (int a = -3; a <= 3; a++) {
            const float* rp = &lx[(row + 3 + a) * 53 + pc0];
            float v[10];
#pragma unroll
            for (int j = 0; j < 10; j++) v[j] = rp[j];
#pragma unroll
            for (int j = 0; j < 4; j++) {
#pragma unroll
                for (int bb = -3; bb <= 3; bb++)
                    c7[j] = fmaf(v[j + 3 + bb], W7[(a + 3) * 7 + (bb + 3)], c7[j]);
                if (a >= -2 && a <= 2) {
#pragma unroll
                    for (int bb = -2; bb <= 2; bb++)
                        c5[j] = fmaf(v[j + 3 + bb], W5[(a + 2) * 5 + (bb + 2)], c5[j]);
                }
                if (a >= -1 && a <= 1) {
#pragma unroll
                    for (int bb = -1; bb <= 1; bb++)
                        c3[j] = fmaf(v[j + 3 + bb], W3[(a + 1) * 3 + (bb + 1)], c3[j]);
                }
                if (a == 0) c1[j] = v[j + 3] * W1;
            }
        }
#pragma unroll
        for (int j = 0; j < 4; j++) {
            int pc = pc0 + j;
            if (pc < 46) {
                int o = row * 47 + pc;
                lxs[0][o] = c1[j] + B1;
                lxs[1][o] = c3[j] + B3;
                lxs[2][o] = c5[j] + B5;
                lxs[3][o] = c7[j] + B7;
            }
        }
    }
    __syncthreads();

    // ---- per-pixel branch machinery ----
    static const int OFFY[8] = {-1, -1, -1, 0, 1, 1, 1, 0};
    static const int OFFX[8] = {-1, 0, 1, 1, 1, 0, -1, -1};

    const float bsc = bns[c], bbi = bnb[c];
    const float bw0 = bw[c * 4 + 0], bw1 = bw[c * 4 + 1];
    const float bw2 = bw[c * 4 + 2], bw3 = bw[c * 4 + 3];

    for (int it = 0; it < 4; it++) {
        int p  = tid + it * 256;
        int ty = p >> 5, tx = p & 31;
        int gy = ty0 + ty, gx = tx0 + tx;
        float br[4];
#pragma unroll
        for (int i = 0; i < 4; i++) {
            const int s = 1 + 2 * i;           // 1,3,5,7
            const float* xs = lxs[i];
            const int base = (ty + 7) * 47 + (tx + 7);
            const float ctr = xs[base];
            float T[8];
#pragma unroll
            for (int k = 0; k < 8; k++) {
                const int dy = OFFY[k] * s, dx = OFFX[k] * s;
                int yy = gy + dy, xx = gx + dx;
                float nb = 0.f;
                if (yy >= 0 && yy < 256 && xx >= 0 && xx < 256)
                    nb = xs[base + dy * 47 + dx];
                T[k] = ctr - nb;
            }
            float S[4];
#pragma unroll
            for (int k = 0; k < 4; k++) S[k] = T[k] + T[k + 4];

            const float w10 = l1w[i * 64 + c * 4 + 0];
            const float w11 = l1w[i * 64 + c * 4 + 1];
            const float w12 = l1w[i * 64 + c * 4 + 2];
            const float w13x2 = 2.f * l1w[i * 64 + c * 4 + 3];
            const float bb1 = l1b[i * 16 + c];

            float o8[8];
#pragma unroll
            for (int k = 0; k < 8; k++) {
                float o = fmaf(S[(k + 1) & 3], w10,
                          fmaf(S[(k + 3) & 3], w11,
                          fmaf(S[(k + 2) & 3], w12,
                          fmaf(T[(k + 4) & 7], w13x2, bb1))));
                o8[k] = o * T[k];
            }
            sort8(o8);
            float acc = l2b[i * 16 + c];
#pragma unroll
            for (int k = 0; k < 8; k++) acc = fmaf(o8[k], l2w[i * 128 + c * 8 + k], acc);
            br[i] = acc;
        }
        sort4(br);
        float yv = fmaf(br[0], bw0, 0.f);
        yv = fmaf(br[1], bw1, yv);
        yv = fmaf(br[2], bw2, yv);
        yv = fmaf(br[3], bw3, yv);
        float z   = fmaf(yv, bsc, bbi);
        float sig = 1.f / (1.f + __expf(-z));
        y16[(long)plane * HW + gy * 256 + gx] = z * sig;
    }
}

// ---------------- K3: final 1x1 16 -> 1 + sigmoid ----------------
__global__ __launch_bounds__(256) void k_final(const float* __restrict__ y16,
                                               const float* __restrict__ fw,
                                               const float* __restrict__ fb,
                                               float* __restrict__ out) {
    long t  = (long)blockIdx.x * 256 + threadIdx.x;   // quad index
    long p0 = t * 4;
    int  b  = (int)(p0 >> 16);
    int  hw = (int)(p0 & 65535);

    const float4* src = (const float4*)(y16 + ((long)b * 16) * HW + hw);
    float fbv = fb[0];
    float4 acc = make_float4(fbv, fbv, fbv, fbv);
#pragma unroll
    for (int cc = 0; cc < 16; cc++) {
        float4 v = src[(long)cc * (HW / 4)];
        float wv = fw[cc];
        acc.x = fmaf(v.x, wv, acc.x);
        acc.y = fmaf(v.y, wv, acc.y);
        acc.z = fmaf(v.z, wv, acc.z);
        acc.w = fmaf(v.w, wv, acc.w);
    }
    float4 r;
    r.x = 1.f / (1.f + __expf(-acc.x));
    r.y = 1.f / (1.f + __expf(-acc.y));
    r.z = 1.f / (1.f + __expf(-acc.z));
    r.w = 1.f / (1.f + __expf(-acc.w));
    ((float4*)out)[t] = r;
}

extern "C" void kernel_launch(void* const* d_in, const int* in_sizes, int n_in,
                              void* d_out, int out_size, void* d_ws, size_t ws_size,
                              hipStream_t stream) {
    const float* cen   = (const float*)d_in[0];
    // d_in[1] = mas (unused by the reference)
    const float* in_w  = (const float*)d_in[2];
    const float* in_b  = (const float*)d_in[3];
    const float* dw_w1 = (const float*)d_in[4];
    const float* dw_b1 = (const float*)d_in[5];
    const float* dw_w3 = (const float*)d_in[6];
    const float* dw_b3 = (const float*)d_in[7];
    const float* dw_w5 = (const float*)d_in[8];
    const float* dw_b5 = (const float*)d_in[9];
    const float* dw_w7 = (const float*)d_in[10];
    const float* dw_b7 = (const float*)d_in[11];
    const float* l1w   = (const float*)d_in[12];
    const float* l1b   = (const float*)d_in[13];
    const float* l2w   = (const float*)d_in[14];
    const float* l2b   = (const float*)d_in[15];
    const float* bw    = (const float*)d_in[16];
    const float* bns   = (const float*)d_in[17];
    const float* bnb   = (const float*)d_in[18];
    const float* fw    = (const float*)d_in[19];
    const float* fb    = (const float*)d_in[20];

    float* x   = (float*)d_ws;                       // (8,16,256,256)  33.5 MB
    float* y16 = x + (size_t)8 * 16 * HW;            // (8,16,256,256)  33.5 MB
    float* out = (float*)d_out;

    k_inconv<<<512, 256, 0, stream>>>(cen, in_w, in_b, x);
    k_main<<<dim3(64, 128), 256, 0, stream>>>(x, dw_w1, dw_b1, dw_w3, dw_b3,
                                              dw_w5, dw_b5, dw_w7, dw_b7,
                                              l1w, l1b, l2w, l2b, bw, bns, bnb, y16);
    k_final<<<512, 256, 0, stream>>>(y16, fw, fb, out);
}

// Round 2
// 457.532 us; speedup vs baseline: 1.0139x; 1.0139x over previous
//
#include <hip/hip_runtime.h>
#include <math.h>

#define HW 65536  // 256*256

// ---------------- K1: in_conv 1x1, 64 -> 16 (float2 per thread) ----------------
__global__ __launch_bounds__(256) void k_inconv(const float* __restrict__ cen,
                                                const float* __restrict__ w,
                                                const float* __restrict__ bias,
                                                float* __restrict__ x) {
    __shared__ float sw[1024];
    __shared__ float sb[16];
    int tid = threadIdx.x;
    for (int i = tid; i < 1024; i += 256) sw[i] = w[i];
    if (tid < 16) sb[tid] = bias[tid];
    __syncthreads();

    long t  = (long)blockIdx.x * 256 + tid;   // pair index
    long p0 = t * 2;                          // first pixel (b*HW + hw)
    int  b  = (int)(p0 >> 16);
    int  hw = (int)(p0 & 65535);

    const float2* src = (const float2*)(cen + ((long)b * 64) * HW + hw);
    float2 acc[16];
#pragma unroll
    for (int o = 0; o < 16; o++) { float bv = sb[o]; acc[o] = make_float2(bv, bv); }

    for (int i = 0; i < 64; i++) {
        float2 v = src[(long)i * (HW / 2)];
#pragma unroll
        for (int o = 0; o < 16; o++) {
            float wv = sw[o * 64 + i];
            acc[o].x = fmaf(v.x, wv, acc[o].x);
            acc[o].y = fmaf(v.y, wv, acc[o].y);
        }
    }
    float2* dst = (float2*)(x + ((long)b * 16) * HW + hw);
#pragma unroll
    for (int o = 0; o < 16; o++) dst[(long)o * (HW / 2)] = acc[o];
}

// ---------------- K2: per-(b,c) fused branch machinery ----------------
#define CE(a, b) { float _lo = fminf(a, b); float _hi = fmaxf(a, b); a = _lo; b = _hi; }

__device__ __forceinline__ void sort8(float* v) {
    CE(v[0], v[1]); CE(v[2], v[3]); CE(v[4], v[5]); CE(v[6], v[7]);
    CE(v[0], v[2]); CE(v[1], v[3]); CE(v[4], v[6]); CE(v[5], v[7]);
    CE(v[1], v[2]); CE(v[5], v[6]); CE(v[0], v[4]); CE(v[3], v[7]);
    CE(v[1], v[5]); CE(v[2], v[6]);
    CE(v[1], v[4]); CE(v[3], v[6]);
    CE(v[2], v[4]); CE(v[3], v[5]);
    CE(v[3], v[4]);
}
__device__ __forceinline__ void sort4(float* v) {
    CE(v[0], v[1]); CE(v[2], v[3]); CE(v[0], v[2]); CE(v[1], v[3]); CE(v[1], v[2]);
}

__global__ __launch_bounds__(256, 3) void k_main(
    const float* __restrict__ x,
    const float* __restrict__ dw_w1, const float* __restrict__ dw_b1,
    const float* __restrict__ dw_w3, const float* __restrict__ dw_b3,
    const float* __restrict__ dw_w5, const float* __restrict__ dw_b5,
    const float* __restrict__ dw_w7, const float* __restrict__ dw_b7,
    const float* __restrict__ l1w, const float* __restrict__ l1b,
    const float* __restrict__ l2w, const float* __restrict__ l2b,
    const float* __restrict__ bw,  const float* __restrict__ bns,
    const float* __restrict__ bnb, float* __restrict__ y16) {

    const int plane = blockIdx.y;          // b*16 + c
    const int c     = plane & 15;
    const int ty0   = (blockIdx.x >> 3) * 32;
    const int tx0   = (blockIdx.x & 7) * 32;
    const int tid   = threadIdx.x;

    __shared__ float lx[53 * 53];          // x tile + halo 10, stride 53
    __shared__ float lxs[4][46 * 47];      // 4 dw-conv outputs (zeroed outside image), stride 47

    const float* xp = x + (long)plane * HW;

    // ---- stage x tile (52x52, origin (ty0-10, tx0-10)), zero outside image ----
    for (int i = tid; i < 52 * 52; i += 256) {
        int r  = i / 52;
        int cc = i - r * 52;
        int gy = ty0 - 10 + r, gx = tx0 - 10 + cc;
        float v = 0.f;
        if ((unsigned)gy < 256u && (unsigned)gx < 256u) v = xp[gy * 256 + gx];
        lx[r * 53 + cc] = v;
    }
    __syncthreads();

    // ---- compute 4 depthwise convs into lxs over 46x46 (tile + halo 7) ----
    // Entries whose global coords fall outside the image are forced to ZERO so
    // the per-pixel neighbor reads need no bounds checks (zero-pad semantics).
    const float* W7 = dw_w7 + c * 49;
    const float* W5 = dw_w5 + c * 25;
    const float* W3 = dw_w3 + c * 9;
    const float  W1 = dw_w1[c];
    const float  B1 = dw_b1[c], B3 = dw_b3[c], B5 = dw_b5[c], B7 = dw_b7[c];

    for (int u = tid; u < 552; u += 256) {      // 46 rows x 12 groups of 4 cols
        int row = u % 46;
        int grp = u / 46;
        int pc0 = grp * 4;
        float c7[4] = {0, 0, 0, 0}, c5[4] = {0, 0, 0, 0}, c3[4] = {0, 0, 0, 0};
        float c1[4] = {0, 0, 0, 0};
#pragma unroll
        for (int a = -3; a <= 3; a++) {
            const float* rp = &lx[(row + 3 + a) * 53 + pc0];
            float v[10];
#pragma unroll
            for (int j = 0; j < 10; j++) v[j] = rp[j];
#pragma unroll
            for (int j = 0; j < 4; j++) {
#pragma unroll
                for (int bb = -3; bb <= 3; bb++)
                    c7[j] = fmaf(v[j + 3 + bb], W7[(a + 3) * 7 + (bb + 3)], c7[j]);
                if (a >= -2 && a <= 2) {
#pragma unroll
                    for (int bb = -2; bb <= 2; bb++)
                        c5[j] = fmaf(v[j + 3 + bb], W5[(a + 2) * 5 + (bb + 2)], c5[j]);
                }
                if (a >= -1 && a <= 1) {
#pragma unroll
                    for (int bb = -1; bb <= 1; bb++)
                        c3[j] = fmaf(v[j + 3 + bb], W3[(a + 1) * 3 + (bb + 1)], c3[j]);
                }
                if (a == 0) c1[j] = v[j + 3] * W1;
            }
        }
        int gy = ty0 - 7 + row;
        bool rowin = ((unsigned)gy < 256u);
#pragma unroll
        for (int j = 0; j < 4; j++) {
            int pc = pc0 + j;
            if (pc < 46) {
                int gx = tx0 - 7 + pc;
                bool in = rowin && ((unsigned)gx < 256u);
                int o = row * 47 + pc;
                lxs[0][o] = in ? c1[j] + B1 : 0.f;
                lxs[1][o] = in ? c3[j] + B3 : 0.f;
                lxs[2][o] = in ? c5[j] + B5 : 0.f;
                lxs[3][o] = in ? c7[j] + B7 : 0.f;
            }
        }
    }
    __syncthreads();

    // ---- per-pixel branch machinery (no bounds checks; imm-offset LDS reads) ----
    constexpr int OFFY[8] = {-1, -1, -1, 0, 1, 1, 1, 0};
    constexpr int OFFX[8] = {-1, 0, 1, 1, 1, 0, -1, -1};

    const float bsc = bns[c], bbi = bnb[c];
    const float bw0 = bw[c * 4 + 0], bw1 = bw[c * 4 + 1];
    const float bw2 = bw[c * 4 + 2], bw3 = bw[c * 4 + 3];

    // hoist per-branch weights
    float w10[4], w11[4], w12[4], w13x2[4], bb1v[4], l2bv[4], l2wv[4][8];
#pragma unroll
    for (int i = 0; i < 4; i++) {
        w10[i]   = l1w[i * 64 + c * 4 + 0];
        w11[i]   = l1w[i * 64 + c * 4 + 1];
        w12[i]   = l1w[i * 64 + c * 4 + 2];
        w13x2[i] = 2.f * l1w[i * 64 + c * 4 + 3];
        bb1v[i]  = l1b[i * 16 + c];
        l2bv[i]  = l2b[i * 16 + c];
#pragma unroll
        for (int k = 0; k < 8; k++) l2wv[i][k] = l2w[i * 128 + c * 8 + k];
    }

    for (int it = 0; it < 4; it++) {
        int p  = tid + it * 256;
        int ty = p >> 5, tx = p & 31;
        int gy = ty0 + ty, gx = tx0 + tx;
        const int corner = ty * 47 + tx;   // lxs coords of (gy-7, gx-7)
        float br[4];
#pragma unroll
        for (int i = 0; i < 4; i++) {
            const int s = 1 + 2 * i;           // 1,3,5,7
            const float* xs = lxs[i];
            const float ctr = xs[corner + 7 * 47 + 7];
            float T[8];
#pragma unroll
            for (int k = 0; k < 8; k++) {
                const int off = (7 + OFFY[k] * s) * 47 + (7 + OFFX[k] * s);  // compile-time, >=0
                T[k] = ctr - xs[corner + off];
            }
            float S[4];
#pragma unroll
            for (int k = 0; k < 4; k++) S[k] = T[k] + T[k + 4];

            float o8[8];
#pragma unroll
            for (int k = 0; k < 8; k++) {
                float o = fmaf(S[(k + 1) & 3], w10[i],
                          fmaf(S[(k + 3) & 3], w11[i],
                          fmaf(S[(k + 2) & 3], w12[i],
                          fmaf(T[(k + 4) & 7], w13x2[i], bb1v[i]))));
                o8[k] = o * T[k];
            }
            sort8(o8);
            float acc = l2bv[i];
#pragma unroll
            for (int k = 0; k < 8; k++) acc = fmaf(o8[k], l2wv[i][k], acc);
            br[i] = acc;
        }
        sort4(br);
        float yv = br[0] * bw0;
        yv = fmaf(br[1], bw1, yv);
        yv = fmaf(br[2], bw2, yv);
        yv = fmaf(br[3], bw3, yv);
        float z   = fmaf(yv, bsc, bbi);
        float sig = 1.f / (1.f + __expf(-z));
        y16[(long)plane * HW + gy * 256 + gx] = z * sig;
    }
}

// ---------------- K3: final 1x1 16 -> 1 + sigmoid ----------------
__global__ __launch_bounds__(256) void k_final(const float* __restrict__ y16,
                                               const float* __restrict__ fw,
                                               const float* __restrict__ fb,
                                               float* __restrict__ out) {
    long t  = (long)blockIdx.x * 256 + threadIdx.x;   // quad index
    long p0 = t * 4;
    int  b  = (int)(p0 >> 16);
    int  hw = (int)(p0 & 65535);

    const float4* src = (const float4*)(y16 + ((long)b * 16) * HW + hw);
    float fbv = fb[0];
    float4 acc = make_float4(fbv, fbv, fbv, fbv);
#pragma unroll
    for (int cc = 0; cc < 16; cc++) {
        float4 v = src[(long)cc * (HW / 4)];
        float wv = fw[cc];
        acc.x = fmaf(v.x, wv, acc.x);
        acc.y = fmaf(v.y, wv, acc.y);
        acc.z = fmaf(v.z, wv, acc.z);
        acc.w = fmaf(v.w, wv, acc.w);
    }
    float4 r;
    r.x = 1.f / (1.f + __expf(-acc.x));
    r.y = 1.f / (1.f + __expf(-acc.y));
    r.z = 1.f / (1.f + __expf(-acc.z));
    r.w = 1.f / (1.f + __expf(-acc.w));
    ((float4*)out)[t] = r;
}

extern "C" void kernel_launch(void* const* d_in, const int* in_sizes, int n_in,
                              void* d_out, int out_size, void* d_ws, size_t ws_size,
                              hipStream_t stream) {
    const float* cen   = (const float*)d_in[0];
    // d_in[1] = mas (unused by the reference)
    const float* in_w  = (const float*)d_in[2];
    const float* in_b  = (const float*)d_in[3];
    const float* dw_w1 = (const float*)d_in[4];
    const float* dw_b1 = (const float*)d_in[5];
    const float* dw_w3 = (const float*)d_in[6];
    const float* dw_b3 = (const float*)d_in[7];
    const float* dw_w5 = (const float*)d_in[8];
    const float* dw_b5 = (const float*)d_in[9];
    const float* dw_w7 = (const float*)d_in[10];
    const float* dw_b7 = (const float*)d_in[11];
    const float* l1w   = (const float*)d_in[12];
    const float* l1b   = (const float*)d_in[13];
    const float* l2w   = (const float*)d_in[14];
    const float* l2b   = (const float*)d_in[15];
    const float* bw    = (const float*)d_in[16];
    const float* bns   = (const float*)d_in[17];
    const float* bnb   = (const float*)d_in[18];
    const float* fw    = (const float*)d_in[19];
    const float* fb    = (const float*)d_in[20];

    float* x   = (float*)d_ws;                       // (8,16,256,256)  33.5 MB
    float* y16 = x + (size_t)8 * 16 * HW;            // (8,16,256,256)  33.5 MB
    float* out = (float*)d_out;

    k_inconv<<<1024, 256, 0, stream>>>(cen, in_w, in_b, x);
    k_main<<<dim3(64, 128), 256, 0, stream>>>(x, dw_w1, dw_b1, dw_w3, dw_b3,
                                              dw_w5, dw_b5, dw_w7, dw_b7,
                                              l1w, l1b, l2w, l2b, bw, bns, bnb, y16);
    k_final<<<512, 256, 0, stream>>>(y16, fw, fb, out);
}